// Round 1
// baseline (22935.193 us; speedup 1.0000x reference)
//
#include <hip/hip_runtime.h>
#include <hip/hip_bf16.h>

// ---------------------------------------------------------------------------
// Model2: 5x true 4-D conv (+ReLU) -> FC(3840->100)+ReLU -> FC(100->1)+sigmoid
// Baseline: direct convolution, one thread per output element, fp32.
// ---------------------------------------------------------------------------

#define BATCH 256

template<int CIN, int COUT, int K, int DIN>
__global__ void conv4d_relu(const float* __restrict__ x,
                            const float* __restrict__ w,
                            const float* __restrict__ bias,
                            float* __restrict__ out) {
    constexpr int DOUT  = DIN - K + 1;
    constexpr int P     = DOUT * DOUT * DOUT * DOUT;   // output spatial size
    constexpr int IN_SP = DIN * DIN * DIN * DIN;       // input spatial size
    constexpr int WSP   = K * K * K * K;               // kernel spatial size

    long long tid   = (long long)blockIdx.x * blockDim.x + threadIdx.x;
    long long total = (long long)BATCH * COUT * P;
    if (tid >= total) return;

    int p  = (int)(tid % P);
    int oc = (int)((tid / P) % COUT);
    int b  = (int)(tid / ((long long)P * COUT));

    int d4 = p % DOUT;
    int d3 = (p / DOUT) % DOUT;
    int d2 = (p / (DOUT * DOUT)) % DOUT;
    int d1 = p / (DOUT * DOUT * DOUT);

    float acc = bias[oc];

    const float* xb = x + (long long)b * CIN * IN_SP
                        + (((d1 * DIN + d2) * DIN + d3) * DIN + d4);
    const float* wo = w + (long long)oc * CIN * WSP;

    for (int i = 0; i < CIN; ++i) {
        const float* xi = xb + i * IN_SP;
        const float* wi = wo + i * WSP;
        for (int k1 = 0; k1 < K; ++k1) {
            for (int k2 = 0; k2 < K; ++k2) {
                #pragma unroll
                for (int k3 = 0; k3 < K; ++k3) {
                    #pragma unroll
                    for (int k4 = 0; k4 < K; ++k4) {
                        float xv = xi[((k1 * DIN + k2) * DIN + k3) * DIN + k4];
                        float wv = wi[((k1 * K + k2) * K + k3) * K + k4];
                        acc = fmaf(xv, wv, acc);
                    }
                }
            }
        }
    }

    out[tid] = fmaxf(acc, 0.0f);
}

// FC1: [B,3840] @ [3840,100] + bias, ReLU.  One block per batch row.
__global__ void fc1_relu(const float* __restrict__ h,
                         const float* __restrict__ w,
                         const float* __restrict__ bias,
                         float* __restrict__ out) {
    int b = blockIdx.x;
    int j = threadIdx.x;
    if (j >= 100) return;
    const float* hb = h + (long long)b * 3840;
    float acc = bias[j];
    for (int d = 0; d < 3840; ++d) {
        acc = fmaf(hb[d], w[d * 100 + j], acc);
    }
    out[b * 100 + j] = fmaxf(acc, 0.0f);
}

// FC2: [B,100] @ [100,1] + bias, sigmoid.  One thread per batch row.
__global__ void fc2_sigmoid(const float* __restrict__ h,
                            const float* __restrict__ w,
                            const float* __restrict__ bias,
                            float* __restrict__ out) {
    int b = blockIdx.x * blockDim.x + threadIdx.x;
    if (b >= BATCH) return;
    const float* hb = h + b * 100;
    float acc = bias[0];
    for (int j = 0; j < 100; ++j) {
        acc = fmaf(hb[j], w[j], acc);
    }
    out[b] = 1.0f / (1.0f + expf(-acc));
}

extern "C" void kernel_launch(void* const* d_in, const int* in_sizes, int n_in,
                              void* d_out, int out_size, void* d_ws, size_t ws_size,
                              hipStream_t stream) {
    const float* x     = (const float*)d_in[0];
    const float* w1    = (const float*)d_in[1];
    const float* b1    = (const float*)d_in[2];
    const float* w2    = (const float*)d_in[3];
    const float* b2    = (const float*)d_in[4];
    const float* w3    = (const float*)d_in[5];
    const float* b3    = (const float*)d_in[6];
    const float* w4    = (const float*)d_in[7];
    const float* b4    = (const float*)d_in[8];
    const float* w5    = (const float*)d_in[9];
    const float* b5    = (const float*)d_in[10];
    const float* fc1w  = (const float*)d_in[11];
    const float* fc1b  = (const float*)d_in[12];
    const float* fc2w  = (const float*)d_in[13];
    const float* fc2b  = (const float*)d_in[14];
    float* out = (float*)d_out;

    // Ping-pong workspace.
    // A holds h1 (256*3*15^4 = 38,880,000 f) then h3, h5.
    // B holds h2 (256*9*12^4 = 47,775,744 f) then h4, fc1 out.
    float* A = (float*)d_ws;
    float* Bb = A + 38880000;   // byte offset 155,520,000 (16B aligned)

    const int TB = 256;
    auto blocks = [](long long n, int tb) { return (int)((n + tb - 1) / tb); };

    // conv1: [256,1,18^4] -> [256,3,15^4]
    {
        long long n = (long long)BATCH * 3 * 15 * 15 * 15 * 15;
        conv4d_relu<1, 3, 4, 18><<<blocks(n, TB), TB, 0, stream>>>(x, w1, b1, A);
    }
    // conv2: -> [256,9,12^4]
    {
        long long n = (long long)BATCH * 9 * 12 * 12 * 12 * 12;
        conv4d_relu<3, 9, 4, 15><<<blocks(n, TB), TB, 0, stream>>>(A, w2, b2, Bb);
    }
    // conv3: -> [256,12,9^4]
    {
        long long n = (long long)BATCH * 12 * 9 * 9 * 9 * 9;
        conv4d_relu<9, 12, 4, 12><<<blocks(n, TB), TB, 0, stream>>>(Bb, w3, b3, A);
    }
    // conv4: -> [256,15,6^4]
    {
        long long n = (long long)BATCH * 15 * 6 * 6 * 6 * 6;
        conv4d_relu<12, 15, 4, 9><<<blocks(n, TB), TB, 0, stream>>>(A, w4, b4, Bb);
    }
    // conv5: -> [256,15,4^4] = [256,3840]
    {
        long long n = (long long)BATCH * 15 * 4 * 4 * 4 * 4;
        conv4d_relu<15, 15, 3, 6><<<blocks(n, TB), TB, 0, stream>>>(Bb, w5, b5, A);
    }
    // fc1: [256,3840] -> [256,100]
    fc1_relu<<<BATCH, 128, 0, stream>>>(A, fc1w, fc1b, Bb);
    // fc2: [256,100] -> [256,1]
    fc2_sigmoid<<<1, BATCH, 0, stream>>>(Bb, fc2w, fc2b, out);
}

// Round 2
// 5182.280 us; speedup vs baseline: 4.4257x; 4.4257x over previous
//
#include <hip/hip_runtime.h>
#include <hip/hip_bf16.h>

// ---------------------------------------------------------------------------
// Model2: 5x true 4-D conv (+ReLU) -> FC(3840->100)+ReLU -> FC(100->1)+sigmoid
// v2: d3-column register tiling. Thread = (b, oc, d1, d2, d4), computes all
// DOUT outputs along d3. Lanes contiguous in d4 -> coalesced loads. Weights
// are wave-uniform (oc from blockIdx) -> scalar s_load. Input rows loaded as
// 4B-aligned dwordx4 via __builtin_memcpy.
// ---------------------------------------------------------------------------

#define BATCH 256

typedef float f32x4 __attribute__((ext_vector_type(4)));

template<int CIN, int COUT, int K, int DIN, int BT>
__launch_bounds__(BT)
__global__ void conv4d_relu_col(const float* __restrict__ x,
                                const float* __restrict__ w,
                                const float* __restrict__ bias,
                                float* __restrict__ out) {
    constexpr int DOUT   = DIN - K + 1;
    constexpr int DOUT3  = DOUT * DOUT * DOUT;            // (d1,d2,d4) triples
    constexpr int CHUNKS = (DOUT3 + BT - 1) / BT;
    constexpr int XD2 = DIN * DIN;
    constexpr int XD1 = DIN * DIN * DIN;
    constexpr int XCI = DIN * DIN * DIN * DIN;
    constexpr int WSP = K * K * K * K;

    int bo    = blockIdx.x / CHUNKS;
    int chunk = blockIdx.x - bo * CHUNKS;
    int oc = bo % COUT;
    int b  = bo / COUT;

    int idx = chunk * BT + threadIdx.x;
    if (idx >= DOUT3) return;
    int d4  = idx % DOUT;          // fastest -> lanes coalesced along d4
    int rem = idx / DOUT;
    int d2  = rem % DOUT;
    int d1  = rem / DOUT;

    const float* xb = x + (size_t)b * CIN * XCI
                        + (size_t)d1 * XD1 + (size_t)d2 * XD2 + d4;
    const float* wo = w + (size_t)oc * CIN * WSP;

    float bv = bias[oc];
    float acc[DOUT];
    #pragma unroll
    for (int t = 0; t < DOUT; ++t) acc[t] = bv;

    #pragma unroll 1
    for (int ci = 0; ci < CIN; ++ci) {
        #pragma unroll 1
        for (int k1 = 0; k1 < K; ++k1) {
            const float* xp = xb + (size_t)ci * XCI + (size_t)k1 * XD1;
            const float* wp = wo + ci * WSP + k1 * (K * K * K);
            #pragma unroll
            for (int k2 = 0; k2 < K; ++k2) {
                const float* xr = xp + k2 * XD2;
                const float* wr = wp + k2 * (K * K);
                float wv[K * K];                      // wave-uniform -> SGPRs
                #pragma unroll
                for (int q = 0; q < K * K; ++q) wv[q] = wr[q];
                #pragma unroll
                for (int r = 0; r < DIN; ++r) {
                    f32x4 xq;                         // one dwordx4 per input row
                    __builtin_memcpy(&xq, xr + r * DIN, sizeof(f32x4));
                    #pragma unroll
                    for (int k3 = 0; k3 < K; ++k3) {
                        int t = r - k3;               // compile-time after unroll
                        if (t >= 0 && t < DOUT) {
                            #pragma unroll
                            for (int k4 = 0; k4 < K; ++k4)
                                acc[t] = fmaf(xq[k4], wv[k3 * K + k4], acc[t]);
                        }
                    }
                }
            }
        }
    }

    float* ob = out + (size_t)(b * COUT + oc) * (DOUT3 * DOUT)
              + (size_t)d1 * (DOUT * DOUT * DOUT) + (size_t)d2 * (DOUT * DOUT) + d4;
    #pragma unroll
    for (int t = 0; t < DOUT; ++t)
        ob[(size_t)t * DOUT] = fmaxf(acc[t], 0.0f);
}

// FC1: [B,3840] @ [3840,100] + bias, ReLU.  One block per batch row.
__global__ void fc1_relu(const float* __restrict__ h,
                         const float* __restrict__ w,
                         const float* __restrict__ bias,
                         float* __restrict__ out) {
    int b = blockIdx.x;
    int j = threadIdx.x;
    if (j >= 100) return;
    const float* hb = h + (size_t)b * 3840;
    float acc = bias[j];
    #pragma unroll 8
    for (int d = 0; d < 3840; ++d)
        acc = fmaf(hb[d], w[d * 100 + j], acc);
    out[b * 100 + j] = fmaxf(acc, 0.0f);
}

// FC2: [B,100] @ [100,1] + bias, sigmoid.  One thread per batch row.
__global__ void fc2_sigmoid(const float* __restrict__ h,
                            const float* __restrict__ w,
                            const float* __restrict__ bias,
                            float* __restrict__ out) {
    int b = blockIdx.x * blockDim.x + threadIdx.x;
    if (b >= BATCH) return;
    const float* hb = h + b * 100;
    float acc = bias[0];
    #pragma unroll
    for (int j = 0; j < 100; ++j)
        acc = fmaf(hb[j], w[j], acc);
    out[b] = 1.0f / (1.0f + expf(-acc));
}

extern "C" void kernel_launch(void* const* d_in, const int* in_sizes, int n_in,
                              void* d_out, int out_size, void* d_ws, size_t ws_size,
                              hipStream_t stream) {
    const float* x    = (const float*)d_in[0];
    const float* w1   = (const float*)d_in[1];
    const float* b1   = (const float*)d_in[2];
    const float* w2   = (const float*)d_in[3];
    const float* b2   = (const float*)d_in[4];
    const float* w3   = (const float*)d_in[5];
    const float* b3   = (const float*)d_in[6];
    const float* w4   = (const float*)d_in[7];
    const float* b4   = (const float*)d_in[8];
    const float* w5   = (const float*)d_in[9];
    const float* b5   = (const float*)d_in[10];
    const float* fc1w = (const float*)d_in[11];
    const float* fc1b = (const float*)d_in[12];
    const float* fc2w = (const float*)d_in[13];
    const float* fc2b = (const float*)d_in[14];
    float* out = (float*)d_out;

    // Ping-pong workspace (same footprint as v1, known to fit):
    // A: h1 (38,880,000 f) -> h3 -> h5;  B: h2 (47,775,744 f) -> h4 -> fc1out.
    float* A  = (float*)d_ws;
    float* Bb = A + 38880000;

    // conv1: [256,1,18^4] -> [256,3,15^4]   DOUT3=3375, CHUNKS=14
    conv4d_relu_col<1, 3, 4, 18, 256><<<256 * 3 * 14, 256, 0, stream>>>(x, w1, b1, A);
    // conv2: -> [256,9,12^4]                DOUT3=1728, CHUNKS=7
    conv4d_relu_col<3, 9, 4, 15, 256><<<256 * 9 * 7, 256, 0, stream>>>(A, w2, b2, Bb);
    // conv3: -> [256,12,9^4]                DOUT3=729, CHUNKS=3
    conv4d_relu_col<9, 12, 4, 12, 256><<<256 * 12 * 3, 256, 0, stream>>>(Bb, w3, b3, A);
    // conv4: -> [256,15,6^4]                DOUT3=216, CHUNKS=1
    conv4d_relu_col<12, 15, 4, 9, 256><<<256 * 15 * 1, 256, 0, stream>>>(A, w4, b4, Bb);
    // conv5: -> [256,15,4^4]                DOUT3=64, CHUNKS=1, BT=64
    conv4d_relu_col<15, 15, 3, 6, 64><<<256 * 15 * 1, 64, 0, stream>>>(Bb, w5, b5, A);
    // fc1: [256,3840] -> [256,100]
    fc1_relu<<<BATCH, 128, 0, stream>>>(A, fc1w, fc1b, Bb);
    // fc2: [256,100] -> [256,1]
    fc2_sigmoid<<<1, BATCH, 0, stream>>>(Bb, fc2w, fc2b, out);
}

// Round 3
// 2225.276 us; speedup vs baseline: 10.3067x; 2.3288x over previous
//
#include <hip/hip_runtime.h>
#include <hip/hip_bf16.h>

// ---------------------------------------------------------------------------
// Model2: 5x true 4-D conv (+ReLU) -> FC(3840->100)+ReLU -> FC(100->1)+sigmoid
// v3: convs 1-4 as implicit-GEMM on MFMA f16 (16x16x32). M = B*P output
// positions, N = 16 (COUT padded), K = CIN*256. Activations fp32 in memory
// (aligned dwordx4 loads), converted to f16 in registers. Weights prepacked
// into MFMA B-fragment order by a tiny prep kernel. conv5 (K=3) + FCs keep
// the v2 VALU path.
// ---------------------------------------------------------------------------

#define BATCH 256

typedef float    f32x4 __attribute__((ext_vector_type(4)));
typedef _Float16 f16x8 __attribute__((ext_vector_type(8)));
typedef unsigned int u32;

// ---------------------------------------------------------------------------
// Weight prepack: WF[kk][lane][j] = W[k][col],  k = kk*32 + (lane>>4)*8 + j,
// col = lane&15 (zero for col >= COUT).  W[k][col] = w[col*KTOT + k].
// ---------------------------------------------------------------------------
template<int COUT>
__global__ void prepack_wf(const float* __restrict__ w,
                           _Float16* __restrict__ wf, int ktot) {
    int idx = blockIdx.x * blockDim.x + threadIdx.x;
    if (idx >= ktot * 16) return;
    int j   = idx & 7;
    int l   = (idx >> 3) & 63;
    int kk  = idx >> 9;
    int k   = kk * 32 + ((l >> 4) << 3) + j;
    int col = l & 15;
    float v = (col < COUT) ? w[col * ktot + k] : 0.0f;
    wf[idx] = (_Float16)v;
}

// ---------------------------------------------------------------------------
// Implicit-GEMM conv (K=4 layers). Each wave owns TILES independent 16-row
// M-tiles; one 16x16 (COUT-padded) output tile per acc.
// ---------------------------------------------------------------------------
template<int CIN, int COUT, int DIN, int TILES>
__launch_bounds__(256)
__global__ void conv4d_mfma(const float* __restrict__ x,
                            const _Float16* __restrict__ wf,
                            const float* __restrict__ bias,
                            float* __restrict__ out) {
    constexpr int DOUT = DIN - 3;
    constexpr u32 P    = (u32)DOUT * DOUT * DOUT * DOUT;
    constexpr u32 M    = (u32)BATCH * P;
    constexpr int XD2  = DIN * DIN;
    constexpr int XD1  = DIN * DIN * DIN;
    constexpr int XCI  = DIN * DIN * DIN * DIN;
    constexpr int KTOT = CIN * 256;
    constexpr int KSTEPS = KTOT / 32;
    constexpr int NENT = KTOT / 8;

    __shared__ u32 offtab[NENT];
    for (int e = threadIdx.x; e < NENT; e += 256) {
        int k0 = e * 8;
        int k3 = (k0 >> 2) & 3;
        int k2 = (k0 >> 4) & 3;
        int k1 = (k0 >> 6) & 3;
        int ci =  k0 >> 8;
        offtab[e] = (u32)(ci * XCI + k1 * XD1 + k2 * XD2 + k3 * DIN) * 4u;
    }
    __syncthreads();

    const int wave = threadIdx.x >> 6;
    const int lane = threadIdx.x & 63;
    const int g    = lane >> 4;        // k-group
    const int r    = lane & 15;        // M-row within tile

    const u32 mt0 = ((u32)blockIdx.x * 64u * TILES) + (u32)wave * 16u * TILES;

    // Per-lane input byte offset of output position m (patch origin, k=0).
    u32 base[TILES];
    #pragma unroll
    for (int t = 0; t < TILES; ++t) {
        u32 m = mt0 + 16u * t + (u32)r;
        if (m > M - 1u) m = M - 1u;
        u32 b   = m / P;
        u32 pos = m - b * P;
        u32 d4 = pos % (u32)DOUT;
        u32 q  = pos / (u32)DOUT;
        u32 d3 = q % (u32)DOUT;  q /= (u32)DOUT;
        u32 d2 = q % (u32)DOUT;
        u32 d1 = q / (u32)DOUT;
        base[t] = (b * (u32)CIN * XCI + d1 * XD1 + d2 * XD2 + d3 * DIN + d4) * 4u;
    }

    const char* xc = (const char*)x;
    const f16x8* wfv = (const f16x8*)wf;

    f32x4 acc[TILES];
    #pragma unroll
    for (int t = 0; t < TILES; ++t) acc[t] = (f32x4){0.f, 0.f, 0.f, 0.f};

    #pragma unroll 2
    for (int kk = 0; kk < KSTEPS; ++kk) {
        u32 off = offtab[(kk << 2) + g];
        f16x8 bfrag = wfv[(kk << 6) + lane];
        #pragma unroll
        for (int t = 0; t < TILES; ++t) {
            f32x4 q0 = *(const f32x4*)(xc + base[t] + off);
            f32x4 q1 = *(const f32x4*)(xc + base[t] + off + DIN * 4);
            f16x8 af;
            #pragma unroll
            for (int i = 0; i < 4; ++i) {
                af[i]     = (_Float16)q0[i];
                af[i + 4] = (_Float16)q1[i];
            }
            acc[t] = __builtin_amdgcn_mfma_f32_16x16x32_f16(af, bfrag, acc[t], 0, 0, 0);
        }
    }

    // Epilogue: D col = lane&15 = oc, row = g*4 + reg.
    const int oc = r;
    if (oc >= COUT) return;
    float bv = bias[oc];
    #pragma unroll
    for (int t = 0; t < TILES; ++t) {
        u32 m0 = mt0 + 16u * t + (u32)(g * 4);
        #pragma unroll
        for (int i = 0; i < 4; ++i) {
            u32 m = m0 + i;
            if (m < M) {
                u32 b   = m / P;
                u32 pos = m - b * P;
                out[((u32)(b * COUT + oc)) * P + pos] = fmaxf(acc[t][i] + bv, 0.0f);
            }
        }
    }
}

// ---------------------------------------------------------------------------
// v2 direct conv (used for conv5, K=3).
// ---------------------------------------------------------------------------
template<int CIN, int COUT, int K, int DIN, int BT>
__launch_bounds__(BT)
__global__ void conv4d_relu_col(const float* __restrict__ x,
                                const float* __restrict__ w,
                                const float* __restrict__ bias,
                                float* __restrict__ out) {
    constexpr int DOUT   = DIN - K + 1;
    constexpr int DOUT3  = DOUT * DOUT * DOUT;
    constexpr int CHUNKS = (DOUT3 + BT - 1) / BT;
    constexpr int XD2 = DIN * DIN;
    constexpr int XD1 = DIN * DIN * DIN;
    constexpr int XCI = DIN * DIN * DIN * DIN;
    constexpr int WSP = K * K * K * K;

    int bo    = blockIdx.x / CHUNKS;
    int chunk = blockIdx.x - bo * CHUNKS;
    int oc = bo % COUT;
    int b  = bo / COUT;

    int idx = chunk * BT + threadIdx.x;
    if (idx >= DOUT3) return;
    int d4  = idx % DOUT;
    int rem = idx / DOUT;
    int d2  = rem % DOUT;
    int d1  = rem / DOUT;

    const float* xb = x + (size_t)b * CIN * XCI
                        + (size_t)d1 * XD1 + (size_t)d2 * XD2 + d4;
    const float* wo = w + (size_t)oc * CIN * WSP;

    float bv = bias[oc];
    float acc[DOUT];
    #pragma unroll
    for (int t = 0; t < DOUT; ++t) acc[t] = bv;

    #pragma unroll 1
    for (int ci = 0; ci < CIN; ++ci) {
        #pragma unroll 1
        for (int k1 = 0; k1 < K; ++k1) {
            const float* xp = xb + (size_t)ci * XCI + (size_t)k1 * XD1;
            const float* wp = wo + ci * WSP + k1 * (K * K * K);
            #pragma unroll
            for (int k2 = 0; k2 < K; ++k2) {
                const float* xr = xp + k2 * XD2;
                const float* wr = wp + k2 * (K * K);
                float wv[K * K];
                #pragma unroll
                for (int q = 0; q < K * K; ++q) wv[q] = wr[q];
                #pragma unroll
                for (int rr = 0; rr < DIN; ++rr) {
                    f32x4 xq;
                    __builtin_memcpy(&xq, xr + rr * DIN, sizeof(f32x4));
                    #pragma unroll
                    for (int k3 = 0; k3 < K; ++k3) {
                        int t = rr - k3;
                        if (t >= 0 && t < DOUT) {
                            #pragma unroll
                            for (int k4 = 0; k4 < K; ++k4)
                                acc[t] = fmaf(xq[k4], wv[k3 * K + k4], acc[t]);
                        }
                    }
                }
            }
        }
    }

    float* ob = out + (size_t)(b * COUT + oc) * (DOUT3 * DOUT)
              + (size_t)d1 * (DOUT * DOUT * DOUT) + (size_t)d2 * (DOUT * DOUT) + d4;
    #pragma unroll
    for (int t = 0; t < DOUT; ++t)
        ob[(size_t)t * DOUT] = fmaxf(acc[t], 0.0f);
}

__global__ void fc1_relu(const float* __restrict__ h,
                         const float* __restrict__ w,
                         const float* __restrict__ bias,
                         float* __restrict__ out) {
    int b = blockIdx.x;
    int j = threadIdx.x;
    if (j >= 100) return;
    const float* hb = h + (size_t)b * 3840;
    float acc = bias[j];
    #pragma unroll 8
    for (int d = 0; d < 3840; ++d)
        acc = fmaf(hb[d], w[d * 100 + j], acc);
    out[b * 100 + j] = fmaxf(acc, 0.0f);
}

__global__ void fc2_sigmoid(const float* __restrict__ h,
                            const float* __restrict__ w,
                            const float* __restrict__ bias,
                            float* __restrict__ out) {
    int b = blockIdx.x * blockDim.x + threadIdx.x;
    if (b >= BATCH) return;
    const float* hb = h + b * 100;
    float acc = bias[0];
    #pragma unroll
    for (int j = 0; j < 100; ++j)
        acc = fmaf(hb[j], w[j], acc);
    out[b] = 1.0f / (1.0f + expf(-acc));
}

extern "C" void kernel_launch(void* const* d_in, const int* in_sizes, int n_in,
                              void* d_out, int out_size, void* d_ws, size_t ws_size,
                              hipStream_t stream) {
    const float* x    = (const float*)d_in[0];
    const float* w1   = (const float*)d_in[1];
    const float* b1   = (const float*)d_in[2];
    const float* w2   = (const float*)d_in[3];
    const float* b2   = (const float*)d_in[4];
    const float* w3   = (const float*)d_in[5];
    const float* b3   = (const float*)d_in[6];
    const float* w4   = (const float*)d_in[7];
    const float* b4   = (const float*)d_in[8];
    const float* w5   = (const float*)d_in[9];
    const float* b5   = (const float*)d_in[10];
    const float* fc1w = (const float*)d_in[11];
    const float* fc1b = (const float*)d_in[12];
    const float* fc2w = (const float*)d_in[13];
    const float* fc2b = (const float*)d_in[14];
    float* out = (float*)d_out;

    // Ping-pong workspace (as v1/v2): A: h1 -> h3 -> h5;  B: h2 -> h4 -> fc1out.
    float* A  = (float*)d_ws;
    float* Bb = A + 38880000;
    // Prepacked weight fragments (f16) in the tail past h2's end (86,655,744 f).
    _Float16* wft = (_Float16*)(A + 86660000);
    _Float16* wf1 = wft;             //  4096 elems
    _Float16* wf2 = wft + 4096;      // 12288
    _Float16* wf3 = wft + 16384;     // 36864
    _Float16* wf4 = wft + 53248;     // 49152

    prepack_wf<3> <<<(256  * 16 + 255) / 256, 256, 0, stream>>>(w1, wf1, 256);
    prepack_wf<9> <<<(768  * 16 + 255) / 256, 256, 0, stream>>>(w2, wf2, 768);
    prepack_wf<12><<<(2304 * 16 + 255) / 256, 256, 0, stream>>>(w3, wf3, 2304);
    prepack_wf<15><<<(3072 * 16 + 255) / 256, 256, 0, stream>>>(w4, wf4, 3072);

    // conv1: M=12,960,000, TILES=4 -> 256 rows/block -> 50625 blocks
    conv4d_mfma<1, 3, 18, 4><<<50625, 256, 0, stream>>>(x, wf1, b1, A);
    // conv2: M=5,308,416, TILES=4 -> 20736 blocks
    conv4d_mfma<3, 9, 15, 4><<<20736, 256, 0, stream>>>(A, wf2, b2, Bb);
    // conv3: M=1,679,616, TILES=2 -> 128 rows/block -> 13122 blocks
    conv4d_mfma<9, 12, 12, 2><<<13122, 256, 0, stream>>>(Bb, wf3, b3, A);
    // conv4: M=331,776, TILES=2 -> 2592 blocks
    conv4d_mfma<12, 15, 9, 2><<<2592, 256, 0, stream>>>(A, wf4, b4, Bb);
    // conv5 (K=3): direct VALU conv
    conv4d_relu_col<15, 15, 3, 6, 64><<<256 * 15, 64, 0, stream>>>(Bb, w5, b5, A);
    fc1_relu<<<BATCH, 128, 0, stream>>>(A, fc1w, fc1b, Bb);
    fc2_sigmoid<<<1, BATCH, 0, stream>>>(Bb, fc2w, fc2b, out);
}

// Round 4
// 1617.852 us; speedup vs baseline: 14.1763x; 1.3755x over previous
//
#include <hip/hip_runtime.h>
#include <hip/hip_bf16.h>

// ---------------------------------------------------------------------------
// Model2: 5x 4-D conv (+ReLU) -> FC(3840->100)+ReLU -> FC(100->1)+sigmoid
// v4: all-f16 activations; all 5 convs as shift-packed implicit-GEMM on
// mfma_f32_32x32x16_f16. N=32 packs S d4-shifts x COUT cols via a k4-extended
// (E=8) window so each lane's A-fragment is one contiguous 16B row segment.
// Inner dims padded to even (DP) + even shift stride S => 4B-aligned loads.
// Weights prepacked to exact B-fragment order (zeros for pad/shift-invalid).
// FC1 on 16x16x32 MFMA. FC2 scalar.
// ---------------------------------------------------------------------------

#define BATCH 256
typedef unsigned int u32;
typedef float    f32x4  __attribute__((ext_vector_type(4)));
typedef float    f32x16 __attribute__((ext_vector_type(16)));
typedef _Float16 f16x8  __attribute__((ext_vector_type(8)));

struct __attribute__((packed, aligned(4))) f16x8w { f16x8 v; };  // 4B-aligned 16B load

// --------------------------- fp32 -> f16 convert ---------------------------
__global__ void cvt_f32_f16(const float* __restrict__ in, _Float16* __restrict__ o, int n8) {
    int i = blockIdx.x * blockDim.x + threadIdx.x;
    if (i >= n8) return;
    const f32x4* p = (const f32x4*)(in + (size_t)i * 8);
    f32x4 a = p[0], b = p[1];
    f16x8 v;
    #pragma unroll
    for (int j = 0; j < 4; ++j) { v[j] = (_Float16)a[j]; v[4 + j] = (_Float16)b[j]; }
    *(f16x8*)(o + (size_t)i * 8) = v;
}

// --------------------------- conv weight prepack ---------------------------
// wf element idx = (st*64 + lane)*8 + j ; k = st*16 + (lane>>5)*8 + j ;
// col = lane&31 = oc*S + s.  B[k,(oc,s)] = w[oc,ci,k1,k2,k3,k4'-s] or 0.
template<int COUT, int CIN, int KS, int K3P, int S>
__global__ void prepack32(const float* __restrict__ w, _Float16* __restrict__ wf) {
    constexpr int KEXT = CIN * KS * KS * K3P * 8;
    int idx = blockIdx.x * 256 + threadIdx.x;
    if (idx >= KEXT * 32) return;
    int j    = idx & 7;
    int lane = (idx >> 3) & 63;
    int st   = idx >> 9;
    int g    = lane >> 5, col = lane & 31;
    int k    = st * 16 + g * 8 + j;
    int k4   = k & 7;
    int e    = k >> 3;
    int k3 = e % K3P;        e /= K3P;
    int k2 = e % KS;         e /= KS;
    int k1 = e % KS;
    int ci = e / KS;
    int oc = col / S, s = col % S;
    int k4s = k4 - s;
    float v = 0.0f;
    if (oc < COUT && k3 < KS && k4s >= 0 && k4s < KS)
        v = w[((((oc * CIN + ci) * KS + k1) * KS + k2) * KS + k3) * KS + k4s];
    wf[idx] = (_Float16)v;
}

// --------------------------- conv kernel (MFMA 32x32x16) -------------------
template<int CIN, int COUT, int KS, int K3P, int DIN, int DP, int S, int OP, int T>
__launch_bounds__(256)
__global__ void conv4d_mfma32(const _Float16* __restrict__ x,
                              const _Float16* __restrict__ wf,
                              const float* __restrict__ bias,
                              _Float16* __restrict__ out) {
    constexpr int DOUT = DIN - KS + 1;
    constexpr int NB   = (DOUT + S - 1) / S;          // shift bases per d3 row
    constexpr int XD2  = DIN * DP;
    constexpr int XD1  = DIN * DIN * DP;
    constexpr int XCI  = DIN * DIN * DIN * DP;
    constexpr int NENT = CIN * KS * KS * K3P;
    constexpr int STEPS = NENT / 2;                   // 16 k's per MFMA step
    constexpr u32 MROWS  = (u32)BATCH * DOUT * DOUT * DOUT * NB;  // /32 exact
    constexpr u32 NTILES = MROWS / 32u;
    constexpr u32 POUT   = (u32)DOUT * DOUT * DOUT * OP;

    __shared__ u32 offtab[NENT];
    for (int e = threadIdx.x; e < NENT; e += 256) {
        int k3 = e % K3P;
        int k2 = (e / K3P) % KS;
        int k1 = (e / (K3P * KS)) % KS;
        int ci =  e / (K3P * KS * KS);
        offtab[e] = (u32)(ci * XCI + k1 * XD1 + k2 * XD2 + k3 * DP) * 2u;
    }
    __syncthreads();

    const int lane = threadIdx.x & 63;
    const int g    = lane >> 5;
    const int r    = lane & 31;

    u32 tt[T];
    u32 base[T];
    u32 tbase = ((u32)blockIdx.x * 4u + (u32)(threadIdx.x >> 6)) * (u32)T;
    #pragma unroll
    for (int t = 0; t < T; ++t) {
        u32 tl = tbase + (u32)t;
        if (tl > NTILES - 1u) tl = NTILES - 1u;       // dup-compute, benign
        tt[t] = tl;
        u32 mr = tl * 32u + (u32)r;
        u32 u  = mr % (u32)NB;  u32 q = mr / (u32)NB;
        u32 d3 = q % (u32)DOUT; q /= (u32)DOUT;
        u32 d2 = q % (u32)DOUT; q /= (u32)DOUT;
        u32 d1 = q % (u32)DOUT; u32 b = q / (u32)DOUT;
        base[t] = (b * (u32)(CIN * XCI) + d1 * (u32)XD1 + d2 * (u32)XD2
                   + d3 * (u32)DP + u * (u32)S) * 2u;
    }

    const char*  xc  = (const char*)x;
    const f16x8* wfv = (const f16x8*)wf;

    f32x16 acc[T];
    #pragma unroll
    for (int t = 0; t < T; ++t)
        #pragma unroll
        for (int i = 0; i < 16; ++i) acc[t][i] = 0.0f;

    #pragma unroll 2
    for (int st = 0; st < STEPS; ++st) {
        u32 off = offtab[2 * st + g];
        f16x8 bf = wfv[(u32)st * 64u + (u32)lane];
        #pragma unroll
        for (int t = 0; t < T; ++t) {
            f16x8 af = ((const f16x8w*)(xc + base[t] + off))->v;
            acc[t] = __builtin_amdgcn_mfma_f32_32x32x16_f16(af, bf, acc[t], 0, 0, 0);
        }
    }

    // Epilogue. D: col = lane&31 = oc*S+s, row = (reg&3) + 8*(reg>>2) + 4*g.
    const int oc = r / S, s = r % S;
    const bool cvalid = (oc < COUT);
    float bv = cvalid ? bias[oc] : 0.0f;
    #pragma unroll
    for (int t = 0; t < T; ++t) {
        #pragma unroll
        for (int reg = 0; reg < 16; ++reg) {
            int rowoff = (reg & 3) + 8 * (reg >> 2) + 4 * g;
            u32 mr = tt[t] * 32u + (u32)rowoff;
            u32 u  = mr % (u32)NB;  u32 q = mr / (u32)NB;
            u32 d3 = q % (u32)DOUT; q /= (u32)DOUT;
            u32 d2 = q % (u32)DOUT; q /= (u32)DOUT;
            u32 d1 = q % (u32)DOUT; u32 b = q / (u32)DOUT;
            u32 d4 = u * (u32)S + (u32)s;
            if (cvalid && d4 < (u32)DOUT) {
                u32 idx = (b * (u32)COUT + (u32)oc) * POUT
                        + ((d1 * (u32)DOUT + d2) * (u32)DOUT + d3) * (u32)OP + d4;
                out[idx] = (_Float16)fmaxf(acc[t][reg] + bv, 0.0f);
            }
        }
    }
}

// --------------------------- FC1 (MFMA 16x16x32) ---------------------------
__global__ void prepack_fc1(const float* __restrict__ w, _Float16* __restrict__ wf) {
    int idx = blockIdx.x * 256 + threadIdx.x;        // 7*120*64*8 = 430080
    if (idx >= 430080) return;
    int j    = idx & 7;
    int lane = (idx >> 3) & 63;
    int t9   = idx >> 9;
    int st   = t9 % 120;
    int ni   = t9 / 120;
    int k    = st * 32 + (lane >> 4) * 8 + j;
    int col  = ni * 16 + (lane & 15);
    wf[idx] = (_Float16)((col < 100) ? w[k * 100 + col] : 0.0f);
}

__launch_bounds__(256)
__global__ void fc1_mfma(const _Float16* __restrict__ h,
                         const _Float16* __restrict__ wfc,
                         const float* __restrict__ bias,
                         float* __restrict__ o) {
    int wv   = blockIdx.x * 4 + (threadIdx.x >> 6);   // 0..111
    int lane = threadIdx.x & 63;
    int r = lane & 15, g = lane >> 4;
    int mi = wv / 7, ni = wv % 7;
    const f16x8* A    = (const f16x8*)(h + (size_t)(mi * 16 + r) * 3840);
    const f16x8* Bv   = (const f16x8*)wfc;
    f32x4 acc = {0.f, 0.f, 0.f, 0.f};
    #pragma unroll 4
    for (int st = 0; st < 120; ++st) {
        f16x8 a = A[st * 4 + g];
        f16x8 b = Bv[(ni * 120 + st) * 64 + lane];
        acc = __builtin_amdgcn_mfma_f32_16x16x32_f16(a, b, acc, 0, 0, 0);
    }
    int col = ni * 16 + r;
    if (col < 100) {
        float bv = bias[col];
        #pragma unroll
        for (int i = 0; i < 4; ++i) {
            int row = mi * 16 + g * 4 + i;
            o[row * 100 + col] = fmaxf(acc[i] + bv, 0.0f);
        }
    }
}

// --------------------------- FC2 + sigmoid ---------------------------------
__global__ void fc2_sigmoid(const float* __restrict__ h,
                            const float* __restrict__ w,
                            const float* __restrict__ bias,
                            float* __restrict__ out) {
    int b = blockIdx.x * blockDim.x + threadIdx.x;
    if (b >= BATCH) return;
    const float* hb = h + b * 100;
    float acc = bias[0];
    #pragma unroll
    for (int j = 0; j < 100; ++j)
        acc = fmaf(hb[j], w[j], acc);
    out[b] = 1.0f / (1.0f + expf(-acc));
}

// --------------------------- launch ----------------------------------------
extern "C" void kernel_launch(void* const* d_in, const int* in_sizes, int n_in,
                              void* d_out, int out_size, void* d_ws, size_t ws_size,
                              hipStream_t stream) {
    const float* x    = (const float*)d_in[0];
    const float* w1   = (const float*)d_in[1];
    const float* b1   = (const float*)d_in[2];
    const float* w2   = (const float*)d_in[3];
    const float* b2   = (const float*)d_in[4];
    const float* w3   = (const float*)d_in[5];
    const float* b3   = (const float*)d_in[6];
    const float* w4   = (const float*)d_in[7];
    const float* b4   = (const float*)d_in[8];
    const float* w5   = (const float*)d_in[9];
    const float* b5   = (const float*)d_in[10];
    const float* fc1w = (const float*)d_in[11];
    const float* fc1b = (const float*)d_in[12];
    const float* fc2w = (const float*)d_in[13];
    const float* fc2b = (const float*)d_in[14];
    float* out = (float*)d_out;

    // f16 workspace allocator (all sizes multiples of 256 elems).
    _Float16* W = (_Float16*)d_ws;
    size_t cur = 0;
    auto alloc = [&](size_t n) { _Float16* p = W + cur; cur += (n + 255) & ~(size_t)255; return p; };
    _Float16* x16 = alloc(26873856);            // [256,1,18,18,18,18]
    _Float16* h1  = alloc(41472000);            // [256,3,15,15,15,(16)]
    _Float16* h2  = alloc(47775744);            // [256,9,12,12,12,12]
    _Float16* h3  = alloc(22394880);            // [256,12,9,9,9,(10)]
    _Float16* h4  = alloc(4976640);             // [256,15,6,6,6,6]
    _Float16* h5  = alloc(983040);              // [256,3840] flatten-exact
    _Float16* wf1 = alloc(16384);               // 512*32
    _Float16* wf2 = alloc(49152);               // 1536*32
    _Float16* wf3 = alloc(147456);              // 4608*32
    _Float16* wf4 = alloc(196608);              // 6144*32
    _Float16* wf5 = alloc(138240);              // 4320*32
    _Float16* wfc = alloc(430080);              // fc1 fragments
    float* fc1out = (float*)alloc(51200 + 256); // [256,100] f32

    // x -> f16
    cvt_f32_f16<<<13122, 256, 0, stream>>>(x, x16, 3359232);

    // weight prepacks
    prepack32<3, 1, 4, 4, 4><<<64,  256, 0, stream>>>(w1, wf1);
    prepack32<9, 3, 4, 4, 2><<<192, 256, 0, stream>>>(w2, wf2);
    prepack32<12, 9, 4, 4, 2><<<576, 256, 0, stream>>>(w3, wf3);
    prepack32<15, 12, 4, 4, 2><<<768, 256, 0, stream>>>(w4, wf4);
    prepack32<15, 15, 3, 4, 2><<<540, 256, 0, stream>>>(w5, wf5);
    prepack_fc1<<<1680, 256, 0, stream>>>(fc1w, wfc);

    // convs:  <CIN,COUT,KS,K3P,DIN,DP,S,OP,T>   grid = ceil(NTILES/16)
    conv4d_mfma32<1, 3, 4, 4, 18, 18, 4, 16, 4><<<6750, 256, 0, stream>>>(x16, wf1, b1, h1);
    conv4d_mfma32<3, 9, 4, 4, 15, 16, 2, 12, 4><<<5184, 256, 0, stream>>>(h1, wf2, b2, h2);
    conv4d_mfma32<9, 12, 4, 4, 12, 12, 2, 10, 4><<<1823, 256, 0, stream>>>(h2, wf3, b3, h3);
    conv4d_mfma32<12, 15, 4, 4, 9, 10, 2, 6, 4><<<324, 256, 0, stream>>>(h3, wf4, b4, h4);
    conv4d_mfma32<15, 15, 3, 4, 6, 6, 2, 4, 4><<<64, 256, 0, stream>>>(h4, wf5, b5, h5);

    // FC1 (28 blocks * 4 waves = 112 tiles = 16 M-tiles x 7 N-tiles)
    fc1_mfma<<<28, 256, 0, stream>>>(h5, wfc, fc1b, fc1out);
    // FC2
    fc2_sigmoid<<<1, 256, 0, stream>>>(fc1out, fc2w, fc2b, out);
}

// Round 5
// 995.995 us; speedup vs baseline: 23.0274x; 1.6244x over previous
//
#include <hip/hip_runtime.h>
#include <hip/hip_bf16.h>

// ---------------------------------------------------------------------------
// Model2: 5x 4-D conv (+ReLU) -> FC(3840->100)+ReLU -> FC(100->1)+sigmoid
// v5: shift-packed implicit-GEMM on mfma_f32_32x32x16_f16 with
//  - d1-tiled A-sharing: wave owns T d1-consecutive tiles; fragment(t,k1)
//    depends only on t+k1 -> (T+KS-1) loads feed T*KS MFMAs (2x fewer A loads)
//  - B fragments staged through LDS double-buffer via global_load_lds
//    (one barrier per CG-group chunk), shared by all 4 waves
//  - global wave-linear tile mapping (fixes small-grid conv4/conv5)
// ---------------------------------------------------------------------------

#define BATCH 256
typedef unsigned int u32;
typedef float    f32x4  __attribute__((ext_vector_type(4)));
typedef float    f32x16 __attribute__((ext_vector_type(16)));
typedef _Float16 f16x8  __attribute__((ext_vector_type(8)));

struct __attribute__((packed, aligned(4))) f16x8w { f16x8 v; };  // 4B-aligned 16B load

// --------------------------- fp32 -> f16 convert ---------------------------
__global__ void cvt_f32_f16(const float* __restrict__ in, _Float16* __restrict__ o, int n8) {
    int i = blockIdx.x * blockDim.x + threadIdx.x;
    if (i >= n8) return;
    const f32x4* p = (const f32x4*)(in + (size_t)i * 8);
    f32x4 a = p[0], b = p[1];
    f16x8 v;
    #pragma unroll
    for (int j = 0; j < 4; ++j) { v[j] = (_Float16)a[j]; v[4 + j] = (_Float16)b[j]; }
    *(f16x8*)(o + (size_t)i * 8) = v;
}

// --------------------------- conv weight prepack ---------------------------
// Step order st = ((ci*KS + k2)*2 + k3p)*KS + k1.  Within a step the 16 k's:
// k_local = g*8 + j  <->  (k3 = 2*k3p + g, k4' = j).  col = lane&31 = oc*S+s.
// B[k,(oc,s)] = w[oc,ci,k1,k2,k3,j-s] (zero outside valid window / pad cols).
template<int COUT, int CIN, int KS, int S>
__global__ void prepack_v5(const float* __restrict__ w, _Float16* __restrict__ wf) {
    constexpr int STEPS = CIN * KS * 2 * KS;
    constexpr int TOT = STEPS * 512;
    int idx = blockIdx.x * 256 + threadIdx.x;
    if (idx >= TOT) return;
    int j    = idx & 7;
    int lane = (idx >> 3) & 63;
    int st   = idx >> 9;
    int k1 = st % KS;
    int r1 = st / KS;
    int k3p = r1 & 1;
    int r2  = r1 >> 1;
    int k2 = r2 % KS;
    int ci = r2 / KS;
    int gg = lane >> 5, col = lane & 31;
    int oc = col / S, s = col % S;
    int k3 = k3p * 2 + gg;
    int k4 = j - s;
    float v = 0.0f;
    if (oc < COUT && k3 < KS && k4 >= 0 && k4 < KS)
        v = w[((((oc * CIN + ci) * KS + k1) * KS + k2) * KS + k3) * KS + k4];
    wf[idx] = (_Float16)v;
}

// --------------------------- LDS staging helper ----------------------------
template<int BYTES>
__device__ __forceinline__ void stage_b(const _Float16* gsrc, char* ldst, int tid) {
    constexpr int N16 = BYTES / 16;
    const int wv = tid >> 6, ln = tid & 63;
    #pragma unroll
    for (int it = 0; it * 256 < N16; ++it) {
        int u16 = it * 256 + (wv << 6);            // wave-uniform 16B-unit index
        if (u16 < N16) {
            const char* gp = (const char*)gsrc + (size_t)(u16 + ln) * 16;
            __builtin_amdgcn_global_load_lds(
                (const __attribute__((address_space(1))) unsigned int*)gp,
                (__attribute__((address_space(3))) unsigned int*)(ldst + u16 * 16),
                16, 0, 0);
        }
    }
}

// --------------------------- conv kernel -----------------------------------
template<int CIN, int COUT, int KS, int DIN, int DP, int S, int OP, int T, int CG>
__launch_bounds__(256, 4)
__global__ void conv4d_v5(const _Float16* __restrict__ x,
                          const _Float16* __restrict__ wf,
                          const float* __restrict__ bias,
                          _Float16* __restrict__ out) {
    constexpr int DOUT = DIN - KS + 1;
    constexpr int NB   = (DOUT + S - 1) / S;
    constexpr int PCOL = DOUT * DOUT * NB;         // (d2,d3,u) rows per (b,d1)
    constexpr int NTC  = (PCOL + 31) / 32;
    constexpr int NG   = DOUT / T;                 // d1 groups
    static_assert(DOUT % T == 0, "T must divide DOUT");
    constexpr int XD2 = DIN * DP;
    constexpr int XD1 = DIN * XD2;
    constexpr int XCI = DIN * XD1;
    constexpr int GROUPS = CIN * KS * 2;
    static_assert(GROUPS % CG == 0, "CG must divide GROUPS");
    constexpr int CSTEPS = CG * KS;
    constexpr int CBYTES = CSTEPS * 1024;
    constexpr int NCHUNK = GROUPS / CG;
    constexpr int AJ = T + KS - 1;
    constexpr u32 NW   = (u32)BATCH * NG * NTC;
    constexpr u32 POUT = (u32)DOUT * DOUT * DOUT * OP;

    __shared__ char bsm[2 * CBYTES];
    const int tid = threadIdx.x;
    u32 wid = blockIdx.x * 4u + (u32)(tid >> 6);
    if (wid >= NW) wid = NW - 1u;
    const int ln = tid & 63;
    const int g  = ln >> 5;
    const int r  = ln & 31;

    u32 tc = wid % (u32)NTC;  u32 q = wid / (u32)NTC;
    u32 d1g = q % (u32)NG;    u32 b = q / (u32)NG;
    u32 rr = tc * 32u + (u32)r;  if (rr >= (u32)PCOL) rr = (u32)PCOL - 1u;
    u32 u  = rr % (u32)NB;    u32 q2 = rr / (u32)NB;
    u32 d3 = q2 % (u32)DOUT;  u32 d2 = q2 / (u32)DOUT;

    const u32 lanebase2 = (b * (u32)(CIN * XCI) + d1g * (u32)(T * XD1)
                         + d2 * (u32)XD2 + d3 * (u32)DP + (u32)(g * DP)
                         + u * (u32)S) * 2u;
    const char* xc = (const char*)x;

    f32x16 acc[T];
    #pragma unroll
    for (int t = 0; t < T; ++t)
        #pragma unroll
        for (int i = 0; i < 16; ++i) acc[t][i] = 0.0f;

    stage_b<CBYTES>(wf, &bsm[0], tid);

    #pragma unroll 1
    for (int ch = 0; ch < NCHUNK; ++ch) {
        __syncthreads();   // compiler drains vmcnt before s_barrier: chunk ch ready
        if (ch + 1 < NCHUNK)
            stage_b<CBYTES>(wf + (size_t)(ch + 1) * CSTEPS * 512,
                            &bsm[((ch + 1) & 1) * CBYTES], tid);
        const char* bb = &bsm[(ch & 1) * CBYTES] + ln * 16;
        #pragma unroll
        for (int gi = 0; gi < CG; ++gi) {
            int grp = ch * CG + gi;
            int k3p = grp & 1;
            int k2  = (grp >> 1) % KS;
            int ci  = (grp >> 1) / KS;
            u32 goff = ((u32)ci * (u32)XCI + (u32)k2 * (u32)XD2
                      + (u32)(k3p * 2 * DP)) * 2u;
            const char* ap = xc + lanebase2 + goff;
            f16x8 ar[AJ];
            #pragma unroll
            for (int j = 0; j < AJ; ++j)
                ar[j] = ((const f16x8w*)(ap + j * (XD1 * 2)))->v;
            #pragma unroll
            for (int k1 = 0; k1 < KS; ++k1) {
                f16x8 bf = *(const f16x8*)(bb + (gi * KS + k1) * 1024);
                #pragma unroll
                for (int t = 0; t < T; ++t)
                    acc[t] = __builtin_amdgcn_mfma_f32_32x32x16_f16(ar[k1 + t], bf, acc[t], 0, 0, 0);
            }
        }
    }

    // Epilogue. D: col = lane&31 = oc*S+s, row = (reg&3) + 8*(reg>>2) + 4*g.
    const int oc = r / S, s = r % S;
    if (oc >= COUT) return;
    float bv = bias[oc];
    #pragma unroll
    for (int t = 0; t < T; ++t) {
        u32 d1 = d1g * (u32)T + (u32)t;
        #pragma unroll
        for (int reg = 0; reg < 16; ++reg) {
            int rowoff = (reg & 3) + 8 * (reg >> 2) + 4 * g;
            u32 rr2 = tc * 32u + (u32)rowoff;
            if (rr2 >= (u32)PCOL) rr2 = (u32)PCOL - 1u;
            u32 uu = rr2 % (u32)NB;  u32 qq = rr2 / (u32)NB;
            u32 dd3 = qq % (u32)DOUT; u32 dd2 = qq / (u32)DOUT;
            u32 d4 = uu * (u32)S + (u32)s;
            if (d4 < (u32)DOUT) {
                u32 oidx = (b * (u32)COUT + (u32)oc) * POUT
                         + ((d1 * (u32)DOUT + dd2) * (u32)DOUT + dd3) * (u32)OP + d4;
                out[oidx] = (_Float16)fmaxf(acc[t][reg] + bv, 0.0f);
            }
        }
    }
}

// --------------------------- FC1 (MFMA 16x16x32) ---------------------------
__global__ void prepack_fc1(const float* __restrict__ w, _Float16* __restrict__ wf) {
    int idx = blockIdx.x * 256 + threadIdx.x;        // 7*120*64*8 = 430080
    if (idx >= 430080) return;
    int j    = idx & 7;
    int lane = (idx >> 3) & 63;
    int t9   = idx >> 9;
    int st   = t9 % 120;
    int ni   = t9 / 120;
    int k    = st * 32 + (lane >> 4) * 8 + j;
    int col  = ni * 16 + (lane & 15);
    wf[idx] = (_Float16)((col < 100) ? w[k * 100 + col] : 0.0f);
}

__launch_bounds__(256)
__global__ void fc1_mfma(const _Float16* __restrict__ h,
                         const _Float16* __restrict__ wfc,
                         const float* __restrict__ bias,
                         float* __restrict__ o) {
    int wv   = blockIdx.x * 4 + (threadIdx.x >> 6);   // 0..111
    int lane = threadIdx.x & 63;
    int r = lane & 15, g = lane >> 4;
    int mi = wv / 7, ni = wv % 7;
    const f16x8* A  = (const f16x8*)(h + (size_t)(mi * 16 + r) * 3840);
    const f16x8* Bv = (const f16x8*)wfc;
    f32x4 acc = {0.f, 0.f, 0.f, 0.f};
    #pragma unroll 4
    for (int st = 0; st < 120; ++st) {
        f16x8 a = A[st * 4 + g];
        f16x8 b = Bv[(ni * 120 + st) * 64 + lane];
        acc = __builtin_amdgcn_mfma_f32_16x16x32_f16(a, b, acc, 0, 0, 0);
    }
    int col = ni * 16 + r;
    if (col < 100) {
        float bv = bias[col];
        #pragma unroll
        for (int i = 0; i < 4; ++i) {
            int row = mi * 16 + g * 4 + i;
            o[row * 100 + col] = fmaxf(acc[i] + bv, 0.0f);
        }
    }
}

// --------------------------- FC2 + sigmoid ---------------------------------
__global__ void fc2_sigmoid(const float* __restrict__ h,
                            const float* __restrict__ w,
                            const float* __restrict__ bias,
                            float* __restrict__ out) {
    int b = blockIdx.x * blockDim.x + threadIdx.x;
    if (b >= BATCH) return;
    const float* hb = h + b * 100;
    float acc = bias[0];
    #pragma unroll
    for (int j = 0; j < 100; ++j)
        acc = fmaf(hb[j], w[j], acc);
    out[b] = 1.0f / (1.0f + expf(-acc));
}

// --------------------------- launch ----------------------------------------
extern "C" void kernel_launch(void* const* d_in, const int* in_sizes, int n_in,
                              void* d_out, int out_size, void* d_ws, size_t ws_size,
                              hipStream_t stream) {
    const float* x    = (const float*)d_in[0];
    const float* w1   = (const float*)d_in[1];
    const float* b1   = (const float*)d_in[2];
    const float* w2   = (const float*)d_in[3];
    const float* b2   = (const float*)d_in[4];
    const float* w3   = (const float*)d_in[5];
    const float* b3   = (const float*)d_in[6];
    const float* w4   = (const float*)d_in[7];
    const float* b4   = (const float*)d_in[8];
    const float* w5   = (const float*)d_in[9];
    const float* b5   = (const float*)d_in[10];
    const float* fc1w = (const float*)d_in[11];
    const float* fc1b = (const float*)d_in[12];
    const float* fc2w = (const float*)d_in[13];
    const float* fc2b = (const float*)d_in[14];
    float* out = (float*)d_out;

    _Float16* W = (_Float16*)d_ws;
    size_t cur = 0;
    auto alloc = [&](size_t n) { _Float16* p = W + cur; cur += (n + 255) & ~(size_t)255; return p; };
    _Float16* x16 = alloc(26873856);            // [256,1,18,18,18,18]
    _Float16* h1  = alloc(41472000);            // [256,3,15,15,15,(16)]
    _Float16* h2  = alloc(47775744);            // [256,9,12,12,12,12]
    _Float16* h3  = alloc(22394880);            // [256,12,9,9,9,(10)]
    _Float16* h4  = alloc(4976640);             // [256,15,6,6,6,6]
    _Float16* h5  = alloc(983040);              // [256,3840] flatten-exact
    _Float16* wf1 = alloc(16384);               // 32 steps * 512
    _Float16* wf2 = alloc(49152);               // 96
    _Float16* wf3 = alloc(147456);              // 288
    _Float16* wf4 = alloc(196608);              // 384
    _Float16* wf5 = alloc(138240);              // 270
    _Float16* wfc = alloc(430080);
    float* fc1out = (float*)alloc(51200 + 256); // [256,100] f32

    cvt_f32_f16<<<13122, 256, 0, stream>>>(x, x16, 3359232);

    prepack_v5<3, 1, 4, 4><<<64,  256, 0, stream>>>(w1, wf1);
    prepack_v5<9, 3, 4, 2><<<192, 256, 0, stream>>>(w2, wf2);
    prepack_v5<12, 9, 4, 2><<<576, 256, 0, stream>>>(w3, wf3);
    prepack_v5<15, 12, 4, 2><<<768, 256, 0, stream>>>(w4, wf4);
    prepack_v5<15, 15, 3, 2><<<540, 256, 0, stream>>>(w5, wf5);
    prepack_fc1<<<1680, 256, 0, stream>>>(fc1w, wfc);

    // convs: <CIN,COUT,KS,DIN,DP,S,OP,T,CG>, grid = NW/4
    // conv1: NTC=29, NG=5  -> NW=37120
    conv4d_v5<1, 3, 4, 18, 18, 4, 16, 3, 4><<<9280, 256, 0, stream>>>(x16, wf1, b1, h1);
    // conv2: NTC=27, NG=4  -> NW=27648
    conv4d_v5<3, 9, 4, 15, 16, 2, 12, 3, 4><<<6912, 256, 0, stream>>>(h1, wf2, b2, h2);
    // conv3: NTC=13, NG=3  -> NW=9984
    conv4d_v5<9, 12, 4, 12, 12, 2, 10, 3, 4><<<2496, 256, 0, stream>>>(h2, wf3, b3, h3);
    // conv4: NTC=4,  NG=2  -> NW=2048
    conv4d_v5<12, 15, 4, 9, 10, 2, 6, 3, 4><<<512, 256, 0, stream>>>(h3, wf4, b4, h4);
    // conv5: NTC=1,  NG=1, T=4 -> NW=256
    conv4d_v5<15, 15, 3, 6, 6, 2, 4, 4, 6><<<64, 256, 0, stream>>>(h4, wf5, b5, h5);

    fc1_mfma<<<28, 256, 0, stream>>>(h5, wfc, fc1b, fc1out);
    fc2_sigmoid<<<1, 256, 0, stream>>>(fc1out, fc2w, fc2b, out);
}